// Round 11
// baseline (195.758 us; speedup 1.0000x reference)
//
#include <hip/hip_runtime.h>
#include <hip/hip_bf16.h>
#include <math.h>

// Problem constants (from reference)
constexpr int NN  = 10000;   // nodes
constexpr int NE  = 160000;  // edges (before self loops)
constexpr int GG  = 16;      // graphs
constexpr int HH  = 4;       // heads
constexpr int FF  = 128;     // per-head channels
constexpr int HF  = 512;     // H*F
constexpr int DS  = 64;      // fixed adjacency stride (max deg ~40 for Poisson(16))

typedef __attribute__((ext_vector_type(8))) short bf16x8;
typedef __attribute__((ext_vector_type(4))) float f32x4;

__device__ inline short f2bf(float v) {
    __hip_bfloat16 h = __float2bfloat16(v);
    return *reinterpret_cast<short*>(&h);
}
__device__ inline float bf2f(short s) {
    __hip_bfloat16 h = *reinterpret_cast<__hip_bfloat16*>(&s);
    return __bfloat162float(h);
}

// ---------------------------------------------------------------------------
// Zero scratch: degs[NN] (scatter cursors) + sums[GG*FF] (pool)
// ---------------------------------------------------------------------------
__global__ __launch_bounds__(256) void zero_kernel(int* __restrict__ degs,
                                                   float* __restrict__ sums) {
    int i = blockIdx.x * 256 + threadIdx.x;
    if (i < NN) degs[i] = 0;
    if (i < GG * FF) sums[i] = 0.f;
}

// ---------------------------------------------------------------------------
// Prep, one launch:
//  z=0..2: W{z} [K,512] fp32 -> W^T bf16 [512,K]
//  z=3   : x -> bf16 (float4 vectorized)
//  z=4   : scatter edges into FIXED-STRIDE adj[dst*64+pos] (no scan needed)
// ---------------------------------------------------------------------------
__global__ __launch_bounds__(256) void prep_scatter(const float* __restrict__ x,
                                                    short* __restrict__ xb,
                                                    const float* __restrict__ W0,
                                                    const float* __restrict__ W1,
                                                    const float* __restrict__ W2,
                                                    short* __restrict__ T0,
                                                    short* __restrict__ T1,
                                                    short* __restrict__ T2,
                                                    const int* __restrict__ ei,
                                                    int* __restrict__ degs,
                                                    int* __restrict__ adj) {
    int z = blockIdx.z;
    int tid = threadIdx.x;
    int bid = blockIdx.y * 16 + blockIdx.x;  // 0..255
    if (z == 3) {
        const float4* x4 = (const float4*)x;
        for (int i = bid * 256 + tid; i < NN * 16; i += 256 * 256) {
            float4 v = x4[i];
            short4 o;
            o.x = f2bf(v.x); o.y = f2bf(v.y); o.z = f2bf(v.z); o.w = f2bf(v.w);
            *(short4*)&xb[i * 4] = o;
        }
        return;
    }
    if (z == 4) {
        for (int e = bid * 256 + tid; e < NE; e += 256 * 256) {
            int dst = ei[NE + e];
            int pos = atomicAdd(&degs[dst], 1);
            if (pos < DS) adj[dst * DS + pos] = ei[e];  // store src
        }
        return;
    }
    const float* W = (z == 0) ? W0 : (z == 1) ? W1 : W2;
    short* T = (z == 0) ? T0 : (z == 1) ? T1 : T2;
    int K = (z == 0) ? 64 : HF;
    int bn = blockIdx.x * 32, bk = blockIdx.y * 32;
    if (bk >= K) return;  // block-uniform
    __shared__ float tile[32][33];
    int tx = tid & 31, ty = tid >> 5;  // ty 0..7
    for (int r = ty; r < 32; r += 8) {
        int k = bk + r, n = bn + tx;
        tile[r][tx] = W[(size_t)k * HF + n];
    }
    __syncthreads();
    for (int r = ty; r < 32; r += 8) {
        int n = bn + r, k = bk + tx;
        T[(size_t)n * K + k] = f2bf(tile[tx][r]);
    }
}

// ---------------------------------------------------------------------------
// bf16 MFMA GEMM + fused attention coefficients.
// C[M,512]bf16 = A[M,K]bf16 @ B[512,K]^T bf16, fp32 accum.
// BM=64, BN=128 = one head, BK=64 (half the barriers of BK=32), 4 waves;
// wave = 64 rows x 32 cols.  1D grid 628 with bijective XCD-chunked mapping:
// each XCD gets a contiguous (bm,head) chunk, head-fastest, so the 4 head
// blocks sharing an A panel land on ONE XCD's L2 (T1, m204 formula).
// Epilogue: es[row,head] = C_row . a_s[head], ed likewise (fp32, exact),
// then C stored as bf16.
// ---------------------------------------------------------------------------
__global__ __launch_bounds__(256) void gemm_attn(const short* __restrict__ A,
                                                 const short* __restrict__ B,
                                                 short* __restrict__ Cb,
                                                 float* __restrict__ es,
                                                 float* __restrict__ ed,
                                                 const float* __restrict__ a_s,
                                                 const float* __restrict__ a_d,
                                                 int M, int K) {
    constexpr int BM = 64, BK = 64, LDT = BK + 8;  // pad 16B
    __shared__ short As[BM][LDT];
    __shared__ short Bh[FF][LDT];
    __shared__ float s_red[4][BM][2];
    int tid = threadIdx.x;
    int wave = tid >> 6, lane = tid & 63;
    int fr = lane & 15, fq = lane >> 4;
    // XCD-chunked bijective mapping: nwg=628 = 4 chunks of 79 + 4 of 78
    int b = blockIdx.x;
    int xcd = b & 7, slot = b >> 3;
    int l = (xcd < 4 ? xcd * 79 : 316 + (xcd - 4) * 78) + slot;
    int bm = (l >> 2) * BM;
    int head = l & 3;
    int bn = head * FF;
    int srow = tid >> 3, scol = (tid & 7) * 8;  // 8 thr/row: 128B contiguous
    f32x4 acc[4][2] = {};
    for (int k0 = 0; k0 < K; k0 += BK) {
#pragma unroll
        for (int p = 0; p < 2; p++) {
            int r = srow + 32 * p;
            int row = bm + r;
            bf16x8 va = {};
            if (row < M) va = *(const bf16x8*)&A[(size_t)row * K + k0 + scol];
            *(bf16x8*)&As[r][scol] = va;
        }
#pragma unroll
        for (int p = 0; p < 4; p++) {
            int r = srow + 32 * p;
            *(bf16x8*)&Bh[r][scol] = *(const bf16x8*)&B[(size_t)(bn + r) * K + k0 + scol];
        }
        __syncthreads();
        bf16x8 af[2][4], bh[2][2];
#pragma unroll
        for (int kk = 0; kk < 2; kk++) {
#pragma unroll
            for (int m = 0; m < 4; m++)
                af[kk][m] = *(const bf16x8*)&As[m * 16 + fr][kk * 32 + fq * 8];
#pragma unroll
            for (int n = 0; n < 2; n++)
                bh[kk][n] = *(const bf16x8*)&Bh[wave * 32 + n * 16 + fr][kk * 32 + fq * 8];
        }
#pragma unroll
        for (int kk = 0; kk < 2; kk++)
#pragma unroll
            for (int m = 0; m < 4; m++)
#pragma unroll
                for (int n = 0; n < 2; n++)
                    acc[m][n] = __builtin_amdgcn_mfma_f32_16x16x32_bf16(af[kk][m], bh[kk][n],
                                                                        acc[m][n], 0, 0, 0);
        __syncthreads();
    }
    // ---- epilogue: fused attn dots + bf16 C store ----
    // C/D layout: col = lane&15, row = (lane>>4)*4 + j   [verified m89]
    float asv[2], adv[2];
#pragma unroll
    for (int n = 0; n < 2; n++) {
        int c = wave * 32 + n * 16 + fr;
        asv[n] = a_s[head * FF + c];
        adv[n] = a_d[head * FF + c];
    }
#pragma unroll
    for (int m = 0; m < 4; m++) {
#pragma unroll
        for (int j = 0; j < 4; j++) {
            float ps = 0.f, pd = 0.f;
#pragma unroll
            for (int n = 0; n < 2; n++) {
                float v = acc[m][n][j];
                ps += v * asv[n];
                pd += v * adv[n];
            }
#pragma unroll
            for (int o = 1; o < 16; o <<= 1) {
                ps += __shfl_xor(ps, o);
                pd += __shfl_xor(pd, o);
            }
            int rloc = m * 16 + fq * 4 + j;
            if (fr == 0) { s_red[wave][rloc][0] = ps; s_red[wave][rloc][1] = pd; }
            int row = bm + rloc;
            if (row < M) {
#pragma unroll
                for (int n = 0; n < 2; n++)
                    Cb[(size_t)row * HF + bn + wave * 32 + n * 16 + fr] = f2bf(acc[m][n][j]);
            }
        }
    }
    __syncthreads();
    if (tid < BM) {
        int row = bm + tid;
        if (row < M) {
            es[row * 4 + head] = s_red[0][tid][0] + s_red[1][tid][0] +
                                 s_red[2][tid][0] + s_red[3][tid][0];
            ed[row * 4 + head] = s_red[0][tid][1] + s_red[1][tid][1] +
                                 s_red[2][tid][1] + s_red[3][tid][1];
        }
    }
}

// ---------------------------------------------------------------------------
// Segment softmax + aggregation. 256 thr = 4 waves, wave = 1 node.
// Fixed-stride adjacency: row n lives at adj[n*64 .. n*64+deg).
// MODE 0: concat + bias + ReLU -> bf16 [N,512]
// MODE 1: head-mean + bias -> fp32 [N,128]
// ---------------------------------------------------------------------------
template <int MODE>
__global__ __launch_bounds__(256) void gat_aggregate(const short* __restrict__ h,
                                                     const float* __restrict__ es,
                                                     const float* __restrict__ ed,
                                                     const int* __restrict__ degs,
                                                     const int* __restrict__ adj,
                                                     const float* __restrict__ bias,
                                                     float* __restrict__ outf,
                                                     short* __restrict__ outb) {
    constexpr int CAP = DS;
    __shared__ int s_src[4][CAP];
    __shared__ float s_wt[4][4][CAP];  // [wave][head][edge]
    int tid = threadIdx.x, w = tid >> 6, lane = tid & 63;
    int n = blockIdx.x * 4 + w;  // grid = NN/4 exactly
    int deg = min(degs[n], CAP - 1);
    int tot = deg + 1;  // + self loop
    if (lane < tot)
        s_src[w][lane] = (lane < deg) ? adj[n * DS + lane] : n;
    float4 edv = *(const float4*)&ed[n * 4];
    float mx0 = -1e30f, mx1 = -1e30f, mx2 = -1e30f, mx3 = -1e30f;
    if (lane < tot) {
        int s = s_src[w][lane];  // written by this same lane
        float4 e4 = *(const float4*)&es[s * 4];
        float e0 = e4.x + edv.x; e0 = (e0 >= 0.f) ? e0 : 0.2f * e0;
        float e1 = e4.y + edv.y; e1 = (e1 >= 0.f) ? e1 : 0.2f * e1;
        float e2 = e4.z + edv.z; e2 = (e2 >= 0.f) ? e2 : 0.2f * e2;
        float e3 = e4.w + edv.w; e3 = (e3 >= 0.f) ? e3 : 0.2f * e3;
        s_wt[w][0][lane] = e0; s_wt[w][1][lane] = e1;
        s_wt[w][2][lane] = e2; s_wt[w][3][lane] = e3;
        mx0 = e0; mx1 = e1; mx2 = e2; mx3 = e3;
    }
#pragma unroll
    for (int o = 1; o < 64; o <<= 1) {
        mx0 = fmaxf(mx0, __shfl_xor(mx0, o));
        mx1 = fmaxf(mx1, __shfl_xor(mx1, o));
        mx2 = fmaxf(mx2, __shfl_xor(mx2, o));
        mx3 = fmaxf(mx3, __shfl_xor(mx3, o));
    }
    float s0 = 0.f, s1 = 0.f, s2 = 0.f, s3 = 0.f;
    if (lane < tot) {
        float v0 = __expf(s_wt[w][0][lane] - mx0); s_wt[w][0][lane] = v0; s0 = v0;
        float v1 = __expf(s_wt[w][1][lane] - mx1); s_wt[w][1][lane] = v1; s1 = v1;
        float v2 = __expf(s_wt[w][2][lane] - mx2); s_wt[w][2][lane] = v2; s2 = v2;
        float v3 = __expf(s_wt[w][3][lane] - mx3); s_wt[w][3][lane] = v3; s3 = v3;
    }
#pragma unroll
    for (int o = 1; o < 64; o <<= 1) {
        s0 += __shfl_xor(s0, o); s1 += __shfl_xor(s1, o);
        s2 += __shfl_xor(s2, o); s3 += __shfl_xor(s3, o);
    }
    __syncthreads();  // cross-lane s_src / s_wt visibility for gather
    int head = lane >> 4;
    float rd = 1.f / ((head == 0) ? s0 : (head == 1) ? s1 : (head == 2) ? s2 : s3);
    float acc[8] = {};
    const short* hbase = h + lane * 8;
#pragma unroll 4
    for (int i = 0; i < tot; i++) {
        int s = s_src[w][i];
        float wt = s_wt[w][head][i];
        bf16x8 hv = *(const bf16x8*)&hbase[(size_t)s * HF];
#pragma unroll
        for (int k = 0; k < 8; k++) acc[k] += wt * bf2f(hv[k]);
    }
#pragma unroll
    for (int k = 0; k < 8; k++) acc[k] *= rd;
    if (MODE == 0) {
        int c = lane * 8;
        float4 b0 = *(const float4*)&bias[c];
        float4 b1 = *(const float4*)&bias[c + 4];
        bf16x8 o;
        o[0] = f2bf(fmaxf(acc[0] + b0.x, 0.f));
        o[1] = f2bf(fmaxf(acc[1] + b0.y, 0.f));
        o[2] = f2bf(fmaxf(acc[2] + b0.z, 0.f));
        o[3] = f2bf(fmaxf(acc[3] + b0.w, 0.f));
        o[4] = f2bf(fmaxf(acc[4] + b1.x, 0.f));
        o[5] = f2bf(fmaxf(acc[5] + b1.y, 0.f));
        o[6] = f2bf(fmaxf(acc[6] + b1.z, 0.f));
        o[7] = f2bf(fmaxf(acc[7] + b1.w, 0.f));
        *(bf16x8*)&outb[(size_t)n * HF + c] = o;
    } else {
        // mean over heads (sum lanes lane^16, lane^32), write fp32 [N,128]
#pragma unroll
        for (int k = 0; k < 8; k++) {
            acc[k] += __shfl_xor(acc[k], 16);
            acc[k] += __shfl_xor(acc[k], 32);
        }
        if (lane < 16) {
            int c = lane * 8;
#pragma unroll
            for (int k = 0; k < 8; k++)
                outf[(size_t)n * FF + c + k] = 0.25f * acc[k] + bias[c + k];
        }
    }
}

// ---------------------------------------------------------------------------
// Global mean pool sums, low-contention: block batches 64 sorted nodes, one
// atomic per (graph-run, channel) => ~40k spread atomics total, 157 blocks.
// ---------------------------------------------------------------------------
__global__ __launch_bounds__(128) void pool_kernel(const float* __restrict__ h2,
                                                   const int* __restrict__ batch,
                                                   float* __restrict__ sums) {
    int f = threadIdx.x;  // 128 threads = feature
    int start = blockIdx.x * 64;
    float acc = 0.f;
    int curg = -1;
    for (int i = 0; i < 64; i++) {
        int node = start + i;
        if (node >= NN) break;
        int g = batch[node];
        if (g != curg) {
            if (curg >= 0) atomicAdd(&sums[curg * FF + f], acc);
            acc = 0.f;
            curg = g;
        }
        acc += h2[(size_t)node * FF + f];
    }
    if (curg >= 0) atomicAdd(&sums[curg * FF + f], acc);
}

// ---------------------------------------------------------------------------
// Final MLP: cnt[g] via binary search on sorted batch (no atomics);
// g = sums/cnt; z = relu(g@Wr1+br1); out = z@Wr2+br2.  Block/graph.
// ---------------------------------------------------------------------------
__global__ __launch_bounds__(256) void mlp_kernel(const float* __restrict__ sums,
                                                  const int* __restrict__ batch,
                                                  const float* __restrict__ Wr1,
                                                  const float* __restrict__ br1,
                                                  const float* __restrict__ Wr2,
                                                  const float* __restrict__ br2,
                                                  float* __restrict__ out) {
    int g = blockIdx.x, t = threadIdx.x;
    __shared__ float gv[128];
    __shared__ float z[128];
    __shared__ float cinv;
    if (t == 0) {
        auto lb = [&](int key) {
            int lo = 0, hi = NN;
            while (lo < hi) { int mid = (lo + hi) >> 1; if (batch[mid] < key) lo = mid + 1; else hi = mid; }
            return lo;
        };
        int cnt = lb(g + 1) - lb(g);
        cinv = 1.0f / fmaxf((float)cnt, 1.0f);
    }
    __syncthreads();
    if (t < 128) gv[t] = sums[g * FF + t] * cinv;
    __syncthreads();
    if (t < 128) {
        float a = br1[t];
        for (int k = 0; k < 128; k++) a += gv[k] * Wr1[k * 128 + t];
        z[t] = fmaxf(a, 0.f);
    }
    __syncthreads();
    {
        float a = br2[t];
        for (int k = 0; k < 128; k++) a += z[k] * Wr2[k * 256 + t];
        out[g * 256 + t] = a;
    }
}

// ---------------------------------------------------------------------------
extern "C" void kernel_launch(void* const* d_in, const int* in_sizes, int n_in,
                              void* d_out, int out_size, void* d_ws, size_t ws_size,
                              hipStream_t stream) {
    const float* x    = (const float*)d_in[0];
    const int*   ei   = (const int*)d_in[1];
    const int*   batch= (const int*)d_in[2];
    const float* W0   = (const float*)d_in[3];
    const float* as0  = (const float*)d_in[4];
    const float* ad0  = (const float*)d_in[5];
    const float* b0   = (const float*)d_in[6];
    const float* W1   = (const float*)d_in[7];
    const float* as1  = (const float*)d_in[8];
    const float* ad1  = (const float*)d_in[9];
    const float* b1   = (const float*)d_in[10];
    const float* W2   = (const float*)d_in[11];
    const float* as2  = (const float*)d_in[12];
    const float* ad2  = (const float*)d_in[13];
    const float* b2   = (const float*)d_in[14];
    const float* Wr1  = (const float*)d_in[15];
    const float* br1  = (const float*)d_in[16];
    const float* Wr2  = (const float*)d_in[17];
    const float* br2  = (const float*)d_in[18];
    float* out = (float*)d_out;

    char* p = (char*)d_ws;
    auto alloc = [&](size_t bytes) {
        char* r = p;
        p += (bytes + 255) / 256 * 256;
        return r;
    };
    short* hA      = (short*)alloc((size_t)NN * HF * 2);   // GEMM out (bf16)
    short* hB      = (short*)alloc((size_t)NN * HF * 2);   // aggregate out (bf16)
    float* h2      = (float*)alloc((size_t)NN * FF * 4);   // layer-2 out (fp32)
    short* xb      = (short*)alloc((size_t)NN * 64 * 2);
    short* T0      = (short*)alloc((size_t)HF * 64 * 2);
    short* T1      = (short*)alloc((size_t)HF * HF * 2);
    short* T2      = (short*)alloc((size_t)HF * HF * 2);
    float* es      = (float*)alloc((size_t)NN * HH * 4);
    float* ed      = (float*)alloc((size_t)NN * HH * 4);
    int*   degs    = (int*)alloc((size_t)NN * 4);
    int*   adj     = (int*)alloc((size_t)NN * DS * 4);
    float* sums    = (float*)alloc((size_t)GG * FF * 4);

    // ---- zero scratch (scatter cursors + pool sums) ----
    zero_kernel<<<(NN + 255) / 256, 256, 0, stream>>>(degs, sums);

    // ---- prep (weight transposes, x->bf16, fixed-stride edge scatter) ----
    prep_scatter<<<dim3(16, 16, 5), 256, 0, stream>>>(x, xb, W0, W1, W2, T0, T1, T2,
                                                      ei, degs, adj);

    int ngemm = ((NN + 63) / 64) * HH;  // 628, 1D grid with XCD-chunked mapping

    // ---- layer 0 (K=64) ----
    gemm_attn<<<ngemm, 256, 0, stream>>>(xb, T0, hA, es, ed, as0, ad0, NN, 64);
    gat_aggregate<0><<<NN / 4, 256, 0, stream>>>(hA, es, ed, degs, adj, b0, nullptr, hB);

    // ---- layer 1 (K=512) ----
    gemm_attn<<<ngemm, 256, 0, stream>>>(hB, T1, hA, es, ed, as1, ad1, NN, HF);
    gat_aggregate<0><<<NN / 4, 256, 0, stream>>>(hA, es, ed, degs, adj, b1, nullptr, hB);

    // ---- layer 2 (K=512) ----
    gemm_attn<<<ngemm, 256, 0, stream>>>(hB, T2, hA, es, ed, as2, ad2, NN, HF);
    gat_aggregate<1><<<NN / 4, 256, 0, stream>>>(hA, es, ed, degs, adj, b2, h2, nullptr);

    // ---- pool (batched atomics over sorted batch) + MLP ----
    pool_kernel<<<(NN + 63) / 64, 128, 0, stream>>>(h2, batch, sums);
    mlp_kernel<<<GG, 256, 0, stream>>>(sums, batch, Wr1, br1, Wr2, br2, out);
}

// Round 12
// 191.567 us; speedup vs baseline: 1.0219x; 1.0219x over previous
//
#include <hip/hip_runtime.h>
#include <hip/hip_bf16.h>
#include <math.h>

// Problem constants (from reference)
constexpr int NN  = 10000;   // nodes
constexpr int NE  = 160000;  // edges (before self loops)
constexpr int GG  = 16;      // graphs
constexpr int HH  = 4;       // heads
constexpr int FF  = 128;     // per-head channels
constexpr int HF  = 512;     // H*F
constexpr int DS  = 64;      // fixed adjacency stride (max deg ~40 for Poisson(16))

typedef __attribute__((ext_vector_type(8))) short bf16x8;
typedef __attribute__((ext_vector_type(4))) float f32x4;

__device__ inline short f2bf(float v) {
    __hip_bfloat16 h = __float2bfloat16(v);
    return *reinterpret_cast<short*>(&h);
}
__device__ inline float bf2f(short s) {
    __hip_bfloat16 h = *reinterpret_cast<__hip_bfloat16*>(&s);
    return __bfloat162float(h);
}

// ---------------------------------------------------------------------------
// Zero scratch: degs[NN] (scatter cursors) + sums[GG*FF] (pool)
// ---------------------------------------------------------------------------
__global__ __launch_bounds__(256) void zero_kernel(int* __restrict__ degs,
                                                   float* __restrict__ sums) {
    int i = blockIdx.x * 256 + threadIdx.x;
    if (i < NN) degs[i] = 0;
    if (i < GG * FF) sums[i] = 0.f;
}

// ---------------------------------------------------------------------------
// Prep, one launch:
//  z=0..2: W{z} [K,512] fp32 -> W^T bf16 [512,K]
//  z=3   : x -> bf16 (float4 vectorized)
//  z=4   : scatter edges into FIXED-STRIDE adj[dst*64+pos] (no scan needed)
// ---------------------------------------------------------------------------
__global__ __launch_bounds__(256) void prep_scatter(const float* __restrict__ x,
                                                    short* __restrict__ xb,
                                                    const float* __restrict__ W0,
                                                    const float* __restrict__ W1,
                                                    const float* __restrict__ W2,
                                                    short* __restrict__ T0,
                                                    short* __restrict__ T1,
                                                    short* __restrict__ T2,
                                                    const int* __restrict__ ei,
                                                    int* __restrict__ degs,
                                                    int* __restrict__ adj) {
    int z = blockIdx.z;
    int tid = threadIdx.x;
    int bid = blockIdx.y * 16 + blockIdx.x;  // 0..255
    if (z == 3) {
        const float4* x4 = (const float4*)x;
        for (int i = bid * 256 + tid; i < NN * 16; i += 256 * 256) {
            float4 v = x4[i];
            short4 o;
            o.x = f2bf(v.x); o.y = f2bf(v.y); o.z = f2bf(v.z); o.w = f2bf(v.w);
            *(short4*)&xb[i * 4] = o;
        }
        return;
    }
    if (z == 4) {
        for (int e = bid * 256 + tid; e < NE; e += 256 * 256) {
            int dst = ei[NE + e];
            int pos = atomicAdd(&degs[dst], 1);
            if (pos < DS) adj[dst * DS + pos] = ei[e];  // store src
        }
        return;
    }
    const float* W = (z == 0) ? W0 : (z == 1) ? W1 : W2;
    short* T = (z == 0) ? T0 : (z == 1) ? T1 : T2;
    int K = (z == 0) ? 64 : HF;
    int bn = blockIdx.x * 32, bk = blockIdx.y * 32;
    if (bk >= K) return;  // block-uniform
    __shared__ float tile[32][33];
    int tx = tid & 31, ty = tid >> 5;  // ty 0..7
    for (int r = ty; r < 32; r += 8) {
        int k = bk + r, n = bn + tx;
        tile[r][tx] = W[(size_t)k * HF + n];
    }
    __syncthreads();
    for (int r = ty; r < 32; r += 8) {
        int n = bn + r, k = bk + tx;
        T[(size_t)n * K + k] = f2bf(tile[tx][r]);
    }
}

// ---------------------------------------------------------------------------
// bf16 MFMA GEMM + fused attention coefficients.  (r10-proven version)
// C[M,512]bf16 = A[M,K]bf16 @ B[512,K]^T bf16, fp32 accum.
// BM=64, BN=128 = one head (blockIdx.y), BK=32, 4 waves; wave = 64 rows x 32
// cols; per K-step: 6 ds_read_b128 + 8 MFMA.  Grid 157x4 = 628 blocks.
// Epilogue: es[row,head] = C_row . a_s[head], ed likewise (fp32, exact),
// then C stored as bf16.
// ---------------------------------------------------------------------------
__global__ __launch_bounds__(256) void gemm_attn(const short* __restrict__ A,
                                                 const short* __restrict__ B,
                                                 short* __restrict__ Cb,
                                                 float* __restrict__ es,
                                                 float* __restrict__ ed,
                                                 const float* __restrict__ a_s,
                                                 const float* __restrict__ a_d,
                                                 int M, int K) {
    constexpr int BM = 64, BK = 32, LDT = BK + 8;  // pad 16B
    __shared__ short As[BM][LDT];
    __shared__ short Bh[FF][LDT];
    __shared__ float s_red[4][BM][2];
    int tid = threadIdx.x;
    int wave = tid >> 6, lane = tid & 63;
    int fr = lane & 15, fq = lane >> 4;
    int bm = blockIdx.x * BM;
    int head = blockIdx.y;
    int bn = head * FF;
    int arow = tid >> 2, acol = (tid & 3) * 8;   // A: 64x32, 8 shorts/thread
    int brow = tid >> 1, bcol = (tid & 1) * 16;  // B: 128x32, 16 shorts/thread
    f32x4 acc[4][2] = {};
    for (int k0 = 0; k0 < K; k0 += BK) {
        {
            int row = bm + arow;
            bf16x8 va = {};
            if (row < M) va = *(const bf16x8*)&A[(size_t)row * K + k0 + acol];
            *(bf16x8*)&As[arow][acol] = va;
            const short* bsh = &B[(size_t)(bn + brow) * K + k0 + bcol];
            *(bf16x8*)&Bh[brow][bcol]     = *(const bf16x8*)bsh;
            *(bf16x8*)&Bh[brow][bcol + 8] = *(const bf16x8*)(bsh + 8);
        }
        __syncthreads();
        bf16x8 af[4], bh[2];
#pragma unroll
        for (int m = 0; m < 4; m++)
            af[m] = *(const bf16x8*)&As[m * 16 + fr][fq * 8];
#pragma unroll
        for (int n = 0; n < 2; n++)
            bh[n] = *(const bf16x8*)&Bh[wave * 32 + n * 16 + fr][fq * 8];
#pragma unroll
        for (int m = 0; m < 4; m++)
#pragma unroll
            for (int n = 0; n < 2; n++)
                acc[m][n] = __builtin_amdgcn_mfma_f32_16x16x32_bf16(af[m], bh[n], acc[m][n], 0, 0, 0);
        __syncthreads();
    }
    // ---- epilogue: fused attn dots + bf16 C store ----
    // C/D layout: col = lane&15, row = (lane>>4)*4 + j   [verified m89]
    float asv[2], adv[2];
#pragma unroll
    for (int n = 0; n < 2; n++) {
        int c = wave * 32 + n * 16 + fr;
        asv[n] = a_s[head * FF + c];
        adv[n] = a_d[head * FF + c];
    }
#pragma unroll
    for (int m = 0; m < 4; m++) {
#pragma unroll
        for (int j = 0; j < 4; j++) {
            float ps = 0.f, pd = 0.f;
#pragma unroll
            for (int n = 0; n < 2; n++) {
                float v = acc[m][n][j];
                ps += v * asv[n];
                pd += v * adv[n];
            }
#pragma unroll
            for (int o = 1; o < 16; o <<= 1) {
                ps += __shfl_xor(ps, o);
                pd += __shfl_xor(pd, o);
            }
            int rloc = m * 16 + fq * 4 + j;
            if (fr == 0) { s_red[wave][rloc][0] = ps; s_red[wave][rloc][1] = pd; }
            int row = bm + rloc;
            if (row < M) {
#pragma unroll
                for (int n = 0; n < 2; n++)
                    Cb[(size_t)row * HF + bn + wave * 32 + n * 16 + fr] = f2bf(acc[m][n][j]);
            }
        }
    }
    __syncthreads();
    if (tid < BM) {
        int row = bm + tid;
        if (row < M) {
            es[row * 4 + head] = s_red[0][tid][0] + s_red[1][tid][0] +
                                 s_red[2][tid][0] + s_red[3][tid][0];
            ed[row * 4 + head] = s_red[0][tid][1] + s_red[1][tid][1] +
                                 s_red[2][tid][1] + s_red[3][tid][1];
        }
    }
}

// ---------------------------------------------------------------------------
// Segment softmax + aggregation. 256 thr = 4 waves, wave = 1 node.
// Fixed-stride adjacency: row n lives at adj[n*64 .. n*64+deg).
// MODE 0: concat + bias + ReLU -> bf16 [N,512]
// MODE 1: head-mean + bias -> fp32 [N,128]
// ---------------------------------------------------------------------------
template <int MODE>
__global__ __launch_bounds__(256) void gat_aggregate(const short* __restrict__ h,
                                                     const float* __restrict__ es,
                                                     const float* __restrict__ ed,
                                                     const int* __restrict__ degs,
                                                     const int* __restrict__ adj,
                                                     const float* __restrict__ bias,
                                                     float* __restrict__ outf,
                                                     short* __restrict__ outb) {
    constexpr int CAP = DS;
    __shared__ int s_src[4][CAP];
    __shared__ float s_wt[4][4][CAP];  // [wave][head][edge]
    int tid = threadIdx.x, w = tid >> 6, lane = tid & 63;
    int n = blockIdx.x * 4 + w;  // grid = NN/4 exactly
    int deg = min(degs[n], CAP - 1);
    int tot = deg + 1;  // + self loop
    if (lane < tot)
        s_src[w][lane] = (lane < deg) ? adj[n * DS + lane] : n;
    float4 edv = *(const float4*)&ed[n * 4];
    float mx0 = -1e30f, mx1 = -1e30f, mx2 = -1e30f, mx3 = -1e30f;
    if (lane < tot) {
        int s = s_src[w][lane];  // written by this same lane
        float4 e4 = *(const float4*)&es[s * 4];
        float e0 = e4.x + edv.x; e0 = (e0 >= 0.f) ? e0 : 0.2f * e0;
        float e1 = e4.y + edv.y; e1 = (e1 >= 0.f) ? e1 : 0.2f * e1;
        float e2 = e4.z + edv.z; e2 = (e2 >= 0.f) ? e2 : 0.2f * e2;
        float e3 = e4.w + edv.w; e3 = (e3 >= 0.f) ? e3 : 0.2f * e3;
        s_wt[w][0][lane] = e0; s_wt[w][1][lane] = e1;
        s_wt[w][2][lane] = e2; s_wt[w][3][lane] = e3;
        mx0 = e0; mx1 = e1; mx2 = e2; mx3 = e3;
    }
#pragma unroll
    for (int o = 1; o < 64; o <<= 1) {
        mx0 = fmaxf(mx0, __shfl_xor(mx0, o));
        mx1 = fmaxf(mx1, __shfl_xor(mx1, o));
        mx2 = fmaxf(mx2, __shfl_xor(mx2, o));
        mx3 = fmaxf(mx3, __shfl_xor(mx3, o));
    }
    float s0 = 0.f, s1 = 0.f, s2 = 0.f, s3 = 0.f;
    if (lane < tot) {
        float v0 = __expf(s_wt[w][0][lane] - mx0); s_wt[w][0][lane] = v0; s0 = v0;
        float v1 = __expf(s_wt[w][1][lane] - mx1); s_wt[w][1][lane] = v1; s1 = v1;
        float v2 = __expf(s_wt[w][2][lane] - mx2); s_wt[w][2][lane] = v2; s2 = v2;
        float v3 = __expf(s_wt[w][3][lane] - mx3); s_wt[w][3][lane] = v3; s3 = v3;
    }
#pragma unroll
    for (int o = 1; o < 64; o <<= 1) {
        s0 += __shfl_xor(s0, o); s1 += __shfl_xor(s1, o);
        s2 += __shfl_xor(s2, o); s3 += __shfl_xor(s3, o);
    }
    __syncthreads();  // cross-lane s_src / s_wt visibility for gather
    int head = lane >> 4;
    float rd = 1.f / ((head == 0) ? s0 : (head == 1) ? s1 : (head == 2) ? s2 : s3);
    float acc[8] = {};
    const short* hbase = h + lane * 8;
#pragma unroll 4
    for (int i = 0; i < tot; i++) {
        int s = s_src[w][i];
        float wt = s_wt[w][head][i];
        bf16x8 hv = *(const bf16x8*)&hbase[(size_t)s * HF];
#pragma unroll
        for (int k = 0; k < 8; k++) acc[k] += wt * bf2f(hv[k]);
    }
#pragma unroll
    for (int k = 0; k < 8; k++) acc[k] *= rd;
    if (MODE == 0) {
        int c = lane * 8;
        float4 b0 = *(const float4*)&bias[c];
        float4 b1 = *(const float4*)&bias[c + 4];
        bf16x8 o;
        o[0] = f2bf(fmaxf(acc[0] + b0.x, 0.f));
        o[1] = f2bf(fmaxf(acc[1] + b0.y, 0.f));
        o[2] = f2bf(fmaxf(acc[2] + b0.z, 0.f));
        o[3] = f2bf(fmaxf(acc[3] + b0.w, 0.f));
        o[4] = f2bf(fmaxf(acc[4] + b1.x, 0.f));
        o[5] = f2bf(fmaxf(acc[5] + b1.y, 0.f));
        o[6] = f2bf(fmaxf(acc[6] + b1.z, 0.f));
        o[7] = f2bf(fmaxf(acc[7] + b1.w, 0.f));
        *(bf16x8*)&outb[(size_t)n * HF + c] = o;
    } else {
        // mean over heads (sum lanes lane^16, lane^32), write fp32 [N,128]
#pragma unroll
        for (int k = 0; k < 8; k++) {
            acc[k] += __shfl_xor(acc[k], 16);
            acc[k] += __shfl_xor(acc[k], 32);
        }
        if (lane < 16) {
            int c = lane * 8;
#pragma unroll
            for (int k = 0; k < 8; k++)
                outf[(size_t)n * FF + c + k] = 0.25f * acc[k] + bias[c + k];
        }
    }
}

// ---------------------------------------------------------------------------
// Global mean pool sums, low-contention: block batches 64 sorted nodes, one
// atomic per (graph-run, channel) => ~40k spread atomics total, 157 blocks.
// ---------------------------------------------------------------------------
__global__ __launch_bounds__(128) void pool_kernel(const float* __restrict__ h2,
                                                   const int* __restrict__ batch,
                                                   float* __restrict__ sums) {
    int f = threadIdx.x;  // 128 threads = feature
    int start = blockIdx.x * 64;
    float acc = 0.f;
    int curg = -1;
    for (int i = 0; i < 64; i++) {
        int node = start + i;
        if (node >= NN) break;
        int g = batch[node];
        if (g != curg) {
            if (curg >= 0) atomicAdd(&sums[curg * FF + f], acc);
            acc = 0.f;
            curg = g;
        }
        acc += h2[(size_t)node * FF + f];
    }
    if (curg >= 0) atomicAdd(&sums[curg * FF + f], acc);
}

// ---------------------------------------------------------------------------
// Final MLP: cnt[g] via binary search on sorted batch (no atomics);
// g = sums/cnt; z = relu(g@Wr1+br1); out = z@Wr2+br2.  Block/graph.
// ---------------------------------------------------------------------------
__global__ __launch_bounds__(256) void mlp_kernel(const float* __restrict__ sums,
                                                  const int* __restrict__ batch,
                                                  const float* __restrict__ Wr1,
                                                  const float* __restrict__ br1,
                                                  const float* __restrict__ Wr2,
                                                  const float* __restrict__ br2,
                                                  float* __restrict__ out) {
    int g = blockIdx.x, t = threadIdx.x;
    __shared__ float gv[128];
    __shared__ float z[128];
    __shared__ float cinv;
    if (t == 0) {
        auto lb = [&](int key) {
            int lo = 0, hi = NN;
            while (lo < hi) { int mid = (lo + hi) >> 1; if (batch[mid] < key) lo = mid + 1; else hi = mid; }
            return lo;
        };
        int cnt = lb(g + 1) - lb(g);
        cinv = 1.0f / fmaxf((float)cnt, 1.0f);
    }
    __syncthreads();
    if (t < 128) gv[t] = sums[g * FF + t] * cinv;
    __syncthreads();
    if (t < 128) {
        float a = br1[t];
        for (int k = 0; k < 128; k++) a += gv[k] * Wr1[k * 128 + t];
        z[t] = fmaxf(a, 0.f);
    }
    __syncthreads();
    {
        float a = br2[t];
        for (int k = 0; k < 128; k++) a += z[k] * Wr2[k * 256 + t];
        out[g * 256 + t] = a;
    }
}

// ---------------------------------------------------------------------------
extern "C" void kernel_launch(void* const* d_in, const int* in_sizes, int n_in,
                              void* d_out, int out_size, void* d_ws, size_t ws_size,
                              hipStream_t stream) {
    const float* x    = (const float*)d_in[0];
    const int*   ei   = (const int*)d_in[1];
    const int*   batch= (const int*)d_in[2];
    const float* W0   = (const float*)d_in[3];
    const float* as0  = (const float*)d_in[4];
    const float* ad0  = (const float*)d_in[5];
    const float* b0   = (const float*)d_in[6];
    const float* W1   = (const float*)d_in[7];
    const float* as1  = (const float*)d_in[8];
    const float* ad1  = (const float*)d_in[9];
    const float* b1   = (const float*)d_in[10];
    const float* W2   = (const float*)d_in[11];
    const float* as2  = (const float*)d_in[12];
    const float* ad2  = (const float*)d_in[13];
    const float* b2   = (const float*)d_in[14];
    const float* Wr1  = (const float*)d_in[15];
    const float* br1  = (const float*)d_in[16];
    const float* Wr2  = (const float*)d_in[17];
    const float* br2  = (const float*)d_in[18];
    float* out = (float*)d_out;

    char* p = (char*)d_ws;
    auto alloc = [&](size_t bytes) {
        char* r = p;
        p += (bytes + 255) / 256 * 256;
        return r;
    };
    short* hA      = (short*)alloc((size_t)NN * HF * 2);   // GEMM out (bf16)
    short* hB      = (short*)alloc((size_t)NN * HF * 2);   // aggregate out (bf16)
    float* h2      = (float*)alloc((size_t)NN * FF * 4);   // layer-2 out (fp32)
    short* xb      = (short*)alloc((size_t)NN * 64 * 2);
    short* T0      = (short*)alloc((size_t)HF * 64 * 2);
    short* T1      = (short*)alloc((size_t)HF * HF * 2);
    short* T2      = (short*)alloc((size_t)HF * HF * 2);
    float* es      = (float*)alloc((size_t)NN * HH * 4);
    float* ed      = (float*)alloc((size_t)NN * HH * 4);
    int*   degs    = (int*)alloc((size_t)NN * 4);
    int*   adj     = (int*)alloc((size_t)NN * DS * 4);
    float* sums    = (float*)alloc((size_t)GG * FF * 4);

    // ---- zero scratch (scatter cursors + pool sums) ----
    zero_kernel<<<(NN + 255) / 256, 256, 0, stream>>>(degs, sums);

    // ---- prep (weight transposes, x->bf16, fixed-stride edge scatter) ----
    prep_scatter<<<dim3(16, 16, 5), 256, 0, stream>>>(x, xb, W0, W1, W2, T0, T1, T2,
                                                      ei, degs, adj);

    dim3 ggemm((NN + 63) / 64, HH);

    // ---- layer 0 (K=64) ----
    gemm_attn<<<ggemm, 256, 0, stream>>>(xb, T0, hA, es, ed, as0, ad0, NN, 64);
    gat_aggregate<0><<<NN / 4, 256, 0, stream>>>(hA, es, ed, degs, adj, b0, nullptr, hB);

    // ---- layer 1 (K=512) ----
    gemm_attn<<<ggemm, 256, 0, stream>>>(hB, T1, hA, es, ed, as1, ad1, NN, HF);
    gat_aggregate<0><<<NN / 4, 256, 0, stream>>>(hA, es, ed, degs, adj, b1, nullptr, hB);

    // ---- layer 2 (K=512) ----
    gemm_attn<<<ggemm, 256, 0, stream>>>(hB, T2, hA, es, ed, as2, ad2, NN, HF);
    gat_aggregate<1><<<NN / 4, 256, 0, stream>>>(hA, es, ed, degs, adj, b2, h2, nullptr);

    // ---- pool (batched atomics over sorted batch) + MLP ----
    pool_kernel<<<(NN + 63) / 64, 128, 0, stream>>>(h2, batch, sums);
    mlp_kernel<<<GG, 256, 0, stream>>>(sums, batch, Wr1, br1, Wr2, br2, out);
}